// Round 9
// baseline (315.466 us; speedup 1.0000x reference)
//
#include <hip/hip_runtime.h>

#define N_ 20480
#define EPS_ 1e-5f

typedef __bf16 bf16;
typedef __attribute__((ext_vector_type(8))) __bf16 bf16x8;
typedef __attribute__((ext_vector_type(4))) __bf16 bf16x4;
typedef __attribute__((ext_vector_type(4))) float f32x4;
typedef __attribute__((ext_vector_type(2))) float f32x2;
typedef __attribute__((ext_vector_type(4))) unsigned short u16x4;

// ---- prep region byte offsets (total 45056 B, then q/k/v bf16 buffers) ----
#define WS_WG1   0        // bf16[4096]  Wg1 rows
#define WS_WG2   8192     // bf16[4096]  Wg2 rows
#define WS_PCST  16384    // f32x4[64]   {Wd2[c][0..2], bd2[c]}
#define WS_L1    17408    // f32x2[64]   {lng1_g, lng1_b}
#define WS_L2    17920    // f32x2[64]   {lng2_g, lng2_b}
#define WS_BG1   18432    // float[64]
#define WS_BG2   18688    // float[64]
#define WS_WQ    18944    // bf16[2048]  folded Wq' = Wq@W1
#define WS_WK    23040    // bf16[2048]
#define WS_WV    27136    // bf16[2048]
#define WS_WSC   31232    // bf16[2048]  BN-scale-folded Wsc'
#define WS_WMLP  35328    // bf16[4096]  BN-scale-folded Wmlp'
#define WS_BQ    43520    // float[64]   folded biases
#define WS_BK    43776
#define WS_BV    44032
#define WS_BSC   44288    // BN offset h for shortcut
#define WS_BMLP  44544    // BN offset h for mlp
#define WS_PD1   44800    // float[18]: Wd1[9], bd1[3], lnd1_g[3], lnd1_b[3]
#define WS_FLAG  44872    // int
#define WS_PREP  45056

template <typename T>
__device__ __forceinline__ float ldf(const T* p, size_t i) { return (float)p[i]; }

__device__ __forceinline__ unsigned short f2bfu(float f) {
  union { __bf16 b; unsigned short u; } cv; cv.b = (__bf16)f; return cv.u;
}

template <typename T>
__device__ __forceinline__ void store4(T* p, float a, float b, float c, float d);
template <>
__device__ __forceinline__ void store4<bf16>(bf16* p, float a, float b, float c, float d) {
  u16x4 v = {f2bfu(a), f2bfu(b), f2bfu(c), f2bfu(d)};
  *(u16x4*)p = v;
}
template <>
__device__ __forceinline__ void store4<float>(float* p, float a, float b, float c, float d) {
  f32x4 v = {a, b, c, d};
  *(f32x4*)p = v;
}

// dtype sniff: bf16 stream -> byte[15:8] of a u32 word is an exponent byte (~99% in [0x30,0x45));
// fp32 stream -> mid-mantissa byte (~8% hit). 4096 words of xyz decide it.
__device__ __forceinline__ int sniff_dtype(const unsigned int* xyz_raw) {
  const int t = threadIdx.x;
  __shared__ int cnt[256];
  int local = 0;
  for (int i = t; i < 4096; i += 256) {
    unsigned int wv = xyz_raw[i];
    unsigned int b1 = (wv >> 8) & 0xFFu;
    local += (b1 >= 0x30u && b1 < 0x45u) ? 1 : 0;
  }
  cnt[t] = local;
  __syncthreads();
  for (int s = 128; s > 0; s >>= 1) {
    if (t < s) cnt[t] += cnt[t + s];
    __syncthreads();
  }
  int r = (cnt[0] > 2048) ? 1 : 0;
  __syncthreads();
  return r;
}

// ---------------- K0: weight prep / folding (grid-stride, 64 blocks; computes flag itself) ----------------
template <typename T>
__device__ void prep_body(const T* W1, const T* b1, const T* Wq, const T* bq,
                          const T* Wk, const T* bk, const T* Wv, const T* bv,
                          const T* Wd1, const T* bd1, const T* lnd1_g, const T* lnd1_b,
                          const T* Wd2, const T* bd2,
                          const T* Wg1, const T* bg1, const T* lng1_g, const T* lng1_b,
                          const T* Wg2, const T* bg2, const T* lng2_g, const T* lng2_b,
                          const T* Wmlp, const T* bnm_g, const T* bnm_b, const T* bnm_m, const T* bnm_v,
                          const T* Wsc, const T* bns_g, const T* bns_b, const T* bns_m, const T* bns_v,
                          char* wsp) {
  const int tid = blockIdx.x * 256 + threadIdx.x;
  const int T_ = gridDim.x * 256;
  bf16* wg1bf = (bf16*)(wsp + WS_WG1);
  bf16* wg2bf = (bf16*)(wsp + WS_WG2);
  bf16* wmlpbf = (bf16*)(wsp + WS_WMLP);
  bf16* wscbf = (bf16*)(wsp + WS_WSC);
  bf16* wqbf = (bf16*)(wsp + WS_WQ);
  bf16* wkbf = (bf16*)(wsp + WS_WK);
  bf16* wvbf = (bf16*)(wsp + WS_WV);
  float* pcst = (float*)(wsp + WS_PCST);
  float* l1c = (float*)(wsp + WS_L1);
  float* l2c = (float*)(wsp + WS_L2);
  float* bg1f = (float*)(wsp + WS_BG1);
  float* bg2f = (float*)(wsp + WS_BG2);
  float* bqf = (float*)(wsp + WS_BQ);
  float* bkf = (float*)(wsp + WS_BK);
  float* bvf = (float*)(wsp + WS_BV);
  float* bscf = (float*)(wsp + WS_BSC);
  float* bmlpf = (float*)(wsp + WS_BMLP);
  float* pd1 = (float*)(wsp + WS_PD1);

  for (int i = tid; i < 4096; i += T_) {
    wg1bf[i] = (__bf16)ldf(Wg1, i);
    wg2bf[i] = (__bf16)ldf(Wg2, i);
    int c = i >> 6;
    float s = ldf(bnm_g, c) * rsqrtf(ldf(bnm_v, c) + EPS_);
    wmlpbf[i] = (__bf16)(s * ldf(Wmlp, i));
  }
  for (int i = tid; i < 2048; i += T_) {
    int c = i >> 5;
    float s = ldf(bns_g, c) * rsqrtf(ldf(bns_v, c) + EPS_);
    wscbf[i] = (__bf16)(s * ldf(Wsc, i));
  }
  // folded q/k/v weights: W' = W @ W1  (64x32)
  for (int o = tid; o < 2048; o += T_) {
    int c = o >> 5, d = o & 31;
    float aq = 0.f, ak = 0.f, av = 0.f;
    for (int cc = 0; cc < 64; ++cc) {
      float w1v = ldf(W1, cc * 32 + d);
      aq = fmaf(ldf(Wq, c * 64 + cc), w1v, aq);
      ak = fmaf(ldf(Wk, c * 64 + cc), w1v, ak);
      av = fmaf(ldf(Wv, c * 64 + cc), w1v, av);
    }
    wqbf[o] = (__bf16)aq; wkbf[o] = (__bf16)ak; wvbf[o] = (__bf16)av;
  }
  if (tid < 64) {
    int t = tid;
    pcst[t * 4 + 0] = ldf(Wd2, t * 3 + 0);
    pcst[t * 4 + 1] = ldf(Wd2, t * 3 + 1);
    pcst[t * 4 + 2] = ldf(Wd2, t * 3 + 2);
    pcst[t * 4 + 3] = ldf(bd2, t);
    l1c[t * 2 + 0] = ldf(lng1_g, t); l1c[t * 2 + 1] = ldf(lng1_b, t);
    l2c[t * 2 + 0] = ldf(lng2_g, t); l2c[t * 2 + 1] = ldf(lng2_b, t);
    bg1f[t] = ldf(bg1, t); bg2f[t] = ldf(bg2, t);
    float aq = ldf(bq, t), ak = ldf(bk, t), av = ldf(bv, t);
    for (int cc = 0; cc < 64; ++cc) {
      float b1v = ldf(b1, cc);
      aq = fmaf(ldf(Wq, t * 64 + cc), b1v, aq);
      ak = fmaf(ldf(Wk, t * 64 + cc), b1v, ak);
      av = fmaf(ldf(Wv, t * 64 + cc), b1v, av);
    }
    bqf[t] = aq; bkf[t] = ak; bvf[t] = av;
    float sm = ldf(bnm_g, t) * rsqrtf(ldf(bnm_v, t) + EPS_);
    bmlpf[t] = ldf(bnm_b, t) - ldf(bnm_m, t) * sm;
    float ss = ldf(bns_g, t) * rsqrtf(ldf(bns_v, t) + EPS_);
    bscf[t] = ldf(bns_b, t) - ldf(bns_m, t) * ss;
  }
  if (tid >= 64 && tid < 64 + 9) pd1[tid - 64] = ldf(Wd1, tid - 64);
  if (tid >= 80 && tid < 83) {
    int i = tid - 80;
    pd1[9 + i] = ldf(bd1, i);
    pd1[12 + i] = ldf(lnd1_g, i);
    pd1[15 + i] = ldf(lnd1_b, i);
  }
}

__launch_bounds__(256)
__global__ void prep_kernel(const void* xyz,
                            const void* W1, const void* b1, const void* Wq, const void* bq,
                            const void* Wk, const void* bk, const void* Wv, const void* bv,
                            const void* Wd1, const void* bd1, const void* lnd1_g, const void* lnd1_b,
                            const void* Wd2, const void* bd2,
                            const void* Wg1, const void* bg1, const void* lng1_g, const void* lng1_b,
                            const void* Wg2, const void* bg2, const void* lng2_g, const void* lng2_b,
                            const void* Wmlp, const void* bnm_g, const void* bnm_b, const void* bnm_m,
                            const void* bnm_v, const void* Wsc, const void* bns_g, const void* bns_b,
                            const void* bns_m, const void* bns_v, char* wsp) {
  int isbf = sniff_dtype((const unsigned int*)xyz);
  if (blockIdx.x == 0 && threadIdx.x == 0) *(int*)(wsp + WS_FLAG) = isbf;
  if (isbf)
    prep_body<bf16>((const bf16*)W1, (const bf16*)b1, (const bf16*)Wq, (const bf16*)bq,
                    (const bf16*)Wk, (const bf16*)bk, (const bf16*)Wv, (const bf16*)bv,
                    (const bf16*)Wd1, (const bf16*)bd1, (const bf16*)lnd1_g, (const bf16*)lnd1_b,
                    (const bf16*)Wd2, (const bf16*)bd2,
                    (const bf16*)Wg1, (const bf16*)bg1, (const bf16*)lng1_g, (const bf16*)lng1_b,
                    (const bf16*)Wg2, (const bf16*)bg2, (const bf16*)lng2_g, (const bf16*)lng2_b,
                    (const bf16*)Wmlp, (const bf16*)bnm_g, (const bf16*)bnm_b, (const bf16*)bnm_m,
                    (const bf16*)bnm_v, (const bf16*)Wsc, (const bf16*)bns_g, (const bf16*)bns_b,
                    (const bf16*)bns_m, (const bf16*)bns_v, wsp);
  else
    prep_body<float>((const float*)W1, (const float*)b1, (const float*)Wq, (const float*)bq,
                     (const float*)Wk, (const float*)bk, (const float*)Wv, (const float*)bv,
                     (const float*)Wd1, (const float*)bd1, (const float*)lnd1_g, (const float*)lnd1_b,
                     (const float*)Wd2, (const float*)bd2,
                     (const float*)Wg1, (const float*)bg1, (const float*)lng1_g, (const float*)lng1_b,
                     (const float*)Wg2, (const float*)bg2, (const float*)lng2_g, (const float*)lng2_b,
                     (const float*)Wmlp, (const float*)bnm_g, (const float*)bnm_b, (const float*)bnm_m,
                     (const float*)bnm_v, (const float*)Wsc, (const float*)bns_g, (const float*)bns_b,
                     (const float*)bns_m, (const float*)bns_v, wsp);
}

// ---------------- K1: MFMA q/k/v (folded weights), wave = 16 points ----------------
template <typename T>
__device__ void xqkv_body(const T* feat, const char* wsp,
                          bf16* q_ws, bf16* k_ws, bf16* v_ws, float (*tile)[68]) {
  const int t = threadIdx.x, w = t >> 6, lane = t & 63;
  const int m = lane & 15, g = lane >> 4;
  const int p0 = blockIdx.x * 64 + w * 16;
  const int b = p0 / N_, n0 = p0 % N_;
  const bf16* wqbf = (const bf16*)(wsp + WS_WQ);
  const bf16* wkbf = (const bf16*)(wsp + WS_WK);
  const bf16* wvbf = (const bf16*)(wsp + WS_WV);
  const float* bqf = (const float*)(wsp + WS_BQ);
  const float* bkf = (const float*)(wsp + WS_BK);
  const float* bvf = (const float*)(wsp + WS_BV);
  float (*tw)[68] = tile + w * 16;

  bf16x8 fa;
  #pragma unroll
  for (int j = 0; j < 8; ++j)
    fa[j] = (__bf16)ldf(feat, ((size_t)b * 32 + g * 8 + j) * N_ + n0 + m);

  auto matmul16 = [&](const bf16* wbf, const float* bias, float* ob) {
    #pragma unroll
    for (int tt = 0; tt < 4; ++tt) {
      bf16x8 wf = *(const bf16x8*)(wbf + (tt * 16 + m) * 32 + g * 8);
      float bb = bias[tt * 16 + m];
      f32x4 ci = {bb, bb, bb, bb};
      ci = __builtin_amdgcn_mfma_f32_16x16x32_bf16(fa, wf, ci, 0, 0, 0);
      #pragma unroll
      for (int r = 0; r < 4; ++r) tw[g * 4 + r][tt * 16 + m] = ci[r];
    }
    #pragma unroll
    for (int s = 0; s < 2; ++s) {
      f32x4 v0 = *(f32x4*)&tw[m][s * 32 + g * 8];
      f32x4 v1 = *(f32x4*)&tw[m][s * 32 + g * 8 + 4];
      #pragma unroll
      for (int r = 0; r < 4; ++r) { ob[s * 8 + r] = v0[r]; ob[s * 8 + 4 + r] = v1[r]; }
    }
  };
  float ob[16];
  bf16x8 o0, o1;
  matmul16(wqbf, bqf, ob);
  #pragma unroll
  for (int j = 0; j < 8; ++j) { o0[j] = (__bf16)ob[j]; o1[j] = (__bf16)ob[8 + j]; }
  *(bf16x8*)(q_ws + (size_t)(p0 + m) * 64 + g * 8) = o0;
  *(bf16x8*)(q_ws + (size_t)(p0 + m) * 64 + 32 + g * 8) = o1;
  matmul16(wkbf, bkf, ob);
  #pragma unroll
  for (int j = 0; j < 8; ++j) { o0[j] = (__bf16)ob[j]; o1[j] = (__bf16)ob[8 + j]; }
  *(bf16x8*)(k_ws + (size_t)(p0 + m) * 64 + g * 8) = o0;
  *(bf16x8*)(k_ws + (size_t)(p0 + m) * 64 + 32 + g * 8) = o1;
  matmul16(wvbf, bvf, ob);
  #pragma unroll
  for (int j = 0; j < 8; ++j) { o0[j] = (__bf16)ob[j]; o1[j] = (__bf16)ob[8 + j]; }
  *(bf16x8*)(v_ws + (size_t)(p0 + m) * 64 + g * 8) = o0;
  *(bf16x8*)(v_ws + (size_t)(p0 + m) * 64 + 32 + g * 8) = o1;
}

__launch_bounds__(256)
__global__ void xqkv_kernel(const void* feat, char* wsp,
                            bf16* q_ws, bf16* k_ws, bf16* v_ws) {
  __shared__ float tile[64][68];
  const int* flag = (const int*)(wsp + WS_FLAG);
  if (flag[0]) xqkv_body<bf16>((const bf16*)feat, wsp, q_ws, k_ws, v_ws, tile);
  else         xqkv_body<float>((const float*)feat, wsp, q_ws, k_ws, v_ws, tile);
}

// ---------------- K2: fused attention + mlp/shortcut epilogue ----------------
// Block = 16 points: 4 waves x 4 sequential points each (unroll 1 -> VGPR stays ~80).
// res goes to an LDS tile; after barrier, wave w computes out-channel tile tt=w and
// stores directly in (B,C,N,1) layout.
template <typename T>
__device__ void attn_body(const T* xyz, const T* feat, const int* nidx, const char* wsp,
                          const bf16* q_ws, const bf16* k_ws, const bf16* v_ws, T* out,
                          f32x4* pcstL, f32x2* l1L, f32x2* l2L,
                          bf16 (*vpf)[72], bf16 (*scr)[72], bf16 (*res_tile)[72]) {
  const int t = threadIdx.x;
  ((float*)pcstL)[t] = ((const float*)(wsp + WS_PCST))[t];
  if (t < 128) ((float*)l1L)[t] = ((const float*)(wsp + WS_L1))[t];
  else if (t < 256) ((float*)l2L)[t - 128] = ((const float*)(wsp + WS_L2))[t - 128];
  __syncthreads();

  const int w = t >> 6, lane = t & 63, m = lane & 15, g = lane >> 4;
  const int p0 = blockIdx.x * 16;
  const int b = p0 / N_, n0 = p0 % N_;
  bf16 (*vw)[72] = vpf + w * 16;
  bf16 (*sw)[72] = scr + w * 16;

  const float* pd1 = (const float*)(wsp + WS_PD1);
  const float* bg1f = (const float*)(wsp + WS_BG1);
  const float* bg2f = (const float*)(wsp + WS_BG2);
  const bf16* wg1bf = (const bf16*)(wsp + WS_WG1);
  const bf16* wg2bf = (const bf16*)(wsp + WS_WG2);

  float bg1r[4], bg2r[4];
  #pragma unroll
  for (int tt = 0; tt < 4; ++tt) { bg1r[tt] = bg1f[tt * 16 + m]; bg2r[tt] = bg2f[tt * 16 + m]; }

  // hoisted feature A-frag for the out phase (independent; HBM latency hidden under attn)
  bf16x8 af;
  #pragma unroll
  for (int j = 0; j < 8; ++j)
    af[j] = (__bf16)ldf(feat, ((size_t)b * 32 + g * 8 + j) * N_ + n0 + m);

  #pragma unroll 1
  for (int it = 0; it < 4; ++it) {
    const int ptl = w * 4 + it;
    const int p = p0 + ptl;

    float xp = ldf(xyz, (size_t)p * 3 + 0);
    float yp = ldf(xyz, (size_t)p * 3 + 1);
    float zp = ldf(xyz, (size_t)p * 3 + 2);

    int idx = nidx[(size_t)p * 16 + m];
    size_t pg = (size_t)b * N_ + idx;
    bf16x8 kf0 = *(const bf16x8*)(k_ws + pg * 64 + g * 8);
    bf16x8 kf1 = *(const bf16x8*)(k_ws + pg * 64 + 32 + g * 8);
    bf16x8 vf0 = *(const bf16x8*)(v_ws + pg * 64 + g * 8);
    bf16x8 vf1 = *(const bf16x8*)(v_ws + pg * 64 + 32 + g * 8);
    bf16x8 qf0 = *(const bf16x8*)(q_ws + (size_t)p * 64 + g * 8);
    bf16x8 qf1 = *(const bf16x8*)(q_ws + (size_t)p * 64 + 32 + g * 8);
    float nx = ldf(xyz, pg * 3 + 0), ny = ldf(xyz, pg * 3 + 1), nz = ldf(xyz, pg * 3 + 2);

    // pos MLP for neighbor m: 3x3 + LN(3) + relu
    float rx = xp - nx, ry = yp - ny, rz = zp - nz;
    float pp0 = pd1[0] * rx + pd1[1] * ry + pd1[2] * rz + pd1[9];
    float pp1 = pd1[3] * rx + pd1[4] * ry + pd1[5] * rz + pd1[10];
    float pp2 = pd1[6] * rx + pd1[7] * ry + pd1[8] * rz + pd1[11];
    float mu3 = (pp0 + pp1 + pp2) * (1.f / 3.f);
    float q0 = pp0 - mu3, q1 = pp1 - mu3, q2 = pp2 - mu3;
    float vr3 = (q0 * q0 + q1 * q1 + q2 * q2) * (1.f / 3.f);
    float rs3 = rsqrtf(vr3 + EPS_);
    float h0 = fmaxf(q0 * rs3 * pd1[12] + pd1[15], 0.f);
    float h1 = fmaxf(q1 * rs3 * pd1[13] + pd1[16], 0.f);
    float h2 = fmaxf(q2 * rs3 * pd1[14] + pd1[17], 0.f);

    float a[16];
    #pragma unroll
    for (int s = 0; s < 2; ++s)
      #pragma unroll
      for (int half = 0; half < 2; ++half) {
        bf16x4 vb;
        #pragma unroll
        for (int q4 = 0; q4 < 4; ++q4) {
          int j = half * 4 + q4;
          int c = s * 32 + g * 8 + j;
          f32x4 pc = pcstL[c];
          float pos = fmaf(h0, pc[0], fmaf(h1, pc[1], fmaf(h2, pc[2], pc[3])));
          float kv = (float)((s == 0) ? kf0[j] : kf1[j]);
          float vv = (float)((s == 0) ? vf0[j] : vf1[j]);
          float qv = (float)((s == 0) ? qf0[j] : qf1[j]);
          vb[q4] = (__bf16)(vv + pos);
          a[s * 8 + j] = qv - kv + pos;
        }
        *(bf16x4*)&vw[m][s * 32 + g * 8 + half * 4] = vb;
      }

    f32x4 acc[4];
    bf16x8 hf0, hf1;

    // LN1 + relu -> A-frags
    {
      float s1 = 0.f, s2 = 0.f;
      #pragma unroll
      for (int i = 0; i < 16; ++i) { s1 += a[i]; s2 = fmaf(a[i], a[i], s2); }
      s1 += __shfl_xor(s1, 16); s2 += __shfl_xor(s2, 16);
      s1 += __shfl_xor(s1, 32); s2 += __shfl_xor(s2, 32);
      float mean = s1 * (1.f / 64.f);
      float var = s2 * (1.f / 64.f) - mean * mean;
      float rsv = rsqrtf(var + EPS_);
      #pragma unroll
      for (int s = 0; s < 2; ++s)
        #pragma unroll
        for (int j = 0; j < 8; ++j) {
          int c = s * 32 + g * 8 + j;
          f32x2 lc = l1L[c];
          float hh = fmaxf(fmaf((a[s * 8 + j] - mean) * rsv, lc[0], lc[1]), 0.f);
          if (s == 0) hf0[j] = (__bf16)hh; else hf1[j] = (__bf16)hh;
        }
    }
    // GEMM1
    #pragma unroll
    for (int tt = 0; tt < 4; ++tt) {
      bf16x8 w0 = *(const bf16x8*)(wg1bf + (tt * 16 + m) * 64 + g * 8);
      bf16x8 w1 = *(const bf16x8*)(wg1bf + (tt * 16 + m) * 64 + 32 + g * 8);
      f32x4 ci = {bg1r[tt], bg1r[tt], bg1r[tt], bg1r[tt]};
      ci = __builtin_amdgcn_mfma_f32_16x16x32_bf16(hf0, w0, ci, 0, 0, 0);
      ci = __builtin_amdgcn_mfma_f32_16x16x32_bf16(hf1, w1, ci, 0, 0, 0);
      acc[tt] = ci;
    }
    // D-layout -> A-layout roundtrip (bf16 LDS, same-wave in-order)
    #pragma unroll
    for (int tt = 0; tt < 4; ++tt)
      #pragma unroll
      for (int r = 0; r < 4; ++r)
        sw[g * 4 + r][tt * 16 + m] = (__bf16)acc[tt][r];
    #pragma unroll
    for (int s = 0; s < 2; ++s) {
      bf16x8 av = *(bf16x8*)&sw[m][s * 32 + g * 8];
      #pragma unroll
      for (int j = 0; j < 8; ++j) a[s * 8 + j] = (float)av[j];
    }
    // LN2 + relu -> A-frags
    {
      float s1 = 0.f, s2 = 0.f;
      #pragma unroll
      for (int i = 0; i < 16; ++i) { s1 += a[i]; s2 = fmaf(a[i], a[i], s2); }
      s1 += __shfl_xor(s1, 16); s2 += __shfl_xor(s2, 16);
      s1 += __shfl_xor(s1, 32); s2 += __shfl_xor(s2, 32);
      float mean = s1 * (1.f / 64.f);
      float var = s2 * (1.f / 64.f) - mean * mean;
      float rsv = rsqrtf(var + EPS_);
      #pragma unroll
      for (int s = 0; s < 2; ++s)
        #pragma unroll
        for (int j = 0; j < 8; ++j) {
          int c = s * 32 + g * 8 + j;
          f32x2 lc = l2L[c];
          float hh = fmaxf(fmaf((a[s * 8 + j] - mean) * rsv, lc[0], lc[1]), 0.f);
          if (s == 0) hf0[j] = (__bf16)hh; else hf1[j] = (__bf16)hh;
        }
    }
    // GEMM2
    #pragma unroll
    for (int tt = 0; tt < 4; ++tt) {
      bf16x8 w0 = *(const bf16x8*)(wg2bf + (tt * 16 + m) * 64 + g * 8);
      bf16x8 w1 = *(const bf16x8*)(wg2bf + (tt * 16 + m) * 64 + 32 + g * 8);
      f32x4 ci = {bg2r[tt], bg2r[tt], bg2r[tt], bg2r[tt]};
      ci = __builtin_amdgcn_mfma_f32_16x16x32_bf16(hf0, w0, ci, 0, 0, 0);
      ci = __builtin_amdgcn_mfma_f32_16x16x32_bf16(hf1, w1, ci, 0, 0, 0);
      acc[tt] = ci;
    }
    // softmax over 16 neighbors + weighted sum of (v+pos)
    float resv[4];
    #pragma unroll
    for (int tt = 0; tt < 4; ++tt) {
      f32x4 l = acc[tt];
      float mx = fmaxf(fmaxf(l[0], l[1]), fmaxf(l[2], l[3]));
      mx = fmaxf(mx, __shfl_xor(mx, 16));
      mx = fmaxf(mx, __shfl_xor(mx, 32));
      float x0 = __expf(l[0] - mx), x1 = __expf(l[1] - mx);
      float x2 = __expf(l[2] - mx), x3 = __expf(l[3] - mx);
      float ss = x0 + x1 + x2 + x3;
      ss += __shfl_xor(ss, 16); ss += __shfl_xor(ss, 32);
      int cc = tt * 16 + m;
      float part = x0 * (float)vw[g * 4 + 0][cc] + x1 * (float)vw[g * 4 + 1][cc]
                 + x2 * (float)vw[g * 4 + 2][cc] + x3 * (float)vw[g * 4 + 3][cc];
      part += __shfl_xor(part, 16); part += __shfl_xor(part, 32);
      resv[tt] = part / ss;
    }
    float outv = (g == 0) ? resv[0] : (g == 1) ? resv[1] : (g == 2) ? resv[2] : resv[3];
    res_tile[ptl][lane] = (__bf16)outv;
  }

  __syncthreads();

  // ---- out phase: wave w = out-channel tile tt=w ----
  const bf16* wmlpbf = (const bf16*)(wsp + WS_WMLP);
  const bf16* wscbf = (const bf16*)(wsp + WS_WSC);
  const float* bmlpf = (const float*)(wsp + WS_BMLP);
  const float* bscf = (const float*)(wsp + WS_BSC);

  bf16x8 ar0 = *(const bf16x8*)&res_tile[m][g * 8];
  bf16x8 ar1 = *(const bf16x8*)&res_tile[m][32 + g * 8];
  bf16x8 wm0 = *(const bf16x8*)(wmlpbf + (w * 16 + m) * 64 + g * 8);
  bf16x8 wm1 = *(const bf16x8*)(wmlpbf + (w * 16 + m) * 64 + 32 + g * 8);
  bf16x8 wsf = *(const bf16x8*)(wscbf + (w * 16 + m) * 32 + g * 8);
  float bm = bmlpf[w * 16 + m], bs = bscf[w * 16 + m];
  f32x4 cm = {bm, bm, bm, bm};
  cm = __builtin_amdgcn_mfma_f32_16x16x32_bf16(ar0, wm0, cm, 0, 0, 0);
  cm = __builtin_amdgcn_mfma_f32_16x16x32_bf16(ar1, wm1, cm, 0, 0, 0);
  f32x4 cs = {bs, bs, bs, bs};
  cs = __builtin_amdgcn_mfma_f32_16x16x32_bf16(af, wsf, cs, 0, 0, 0);
  float o[4];
  #pragma unroll
  for (int r = 0; r < 4; ++r) {
    float v = fmaxf(cm[r], 0.f) + fmaxf(cs[r], 0.f);
    o[r] = (v > 0.f) ? v : 0.2f * v;
  }
  // D rows g*4+r = points p0+g*4+r; col = channel w*16+m
  store4(out + ((size_t)b * 64 + w * 16 + m) * N_ + n0 + g * 4, o[0], o[1], o[2], o[3]);
}

__launch_bounds__(256)
__global__ void attn_kernel(const void* xyz, const void* feat, const int* __restrict__ nidx,
                            char* wsp, const bf16* q_ws, const bf16* k_ws, const bf16* v_ws,
                            void* out) {
  __shared__ f32x4 pcstL[64];       // 1024 B
  __shared__ f32x2 l1L[64];         // 512 B
  __shared__ f32x2 l2L[64];         // 512 B
  __shared__ bf16 vpf[64][72];      // 9216 B
  __shared__ bf16 scr[64][72];      // 9216 B
  __shared__ bf16 res_tile[16][72]; // 2304 B -> total 22784 B -> 7 blocks/CU
  const int* flag = (const int*)(wsp + WS_FLAG);
  if (flag[0])
    attn_body<bf16>((const bf16*)xyz, (const bf16*)feat, nidx, wsp, q_ws, k_ws, v_ws,
                    (bf16*)out, pcstL, l1L, l2L, vpf, scr, res_tile);
  else
    attn_body<float>((const float*)xyz, (const float*)feat, nidx, wsp, q_ws, k_ws, v_ws,
                     (float*)out, pcstL, l1L, l2L, vpf, scr, res_tile);
}

// ---------------- launcher ----------------
extern "C" void kernel_launch(void* const* d_in, const int* in_sizes, int n_in,
                              void* d_out, int out_size, void* d_ws, size_t ws_size,
                              hipStream_t stream) {
  const void* feature = d_in[0];
  const void* xyz     = d_in[1];
  const int*  nidx    = (const int*)d_in[34];

  char* ws = (char*)d_ws;
  bf16* q_ws = (bf16*)(ws + WS_PREP);                 // 5,242,880 B
  bf16* k_ws = (bf16*)(ws + WS_PREP + 5242880);       // 5,242,880 B
  bf16* v_ws = (bf16*)(ws + WS_PREP + 10485760);      // 5,242,880 B  -> total 15.8 MB

  prep_kernel<<<64, 256, 0, stream>>>(xyz,
                                      d_in[2], d_in[3], d_in[4], d_in[5], d_in[6], d_in[7],
                                      d_in[8], d_in[9], d_in[10], d_in[11], d_in[12], d_in[13],
                                      d_in[14], d_in[15], d_in[16], d_in[17], d_in[18], d_in[19],
                                      d_in[20], d_in[21], d_in[22], d_in[23], d_in[24], d_in[25],
                                      d_in[26], d_in[27], d_in[28], d_in[29], d_in[30], d_in[31],
                                      d_in[32], d_in[33], ws);
  xqkv_kernel<<<640, 256, 0, stream>>>(feature, ws, q_ws, k_ws, v_ws);
  attn_kernel<<<2560, 256, 0, stream>>>(xyz, feature, nidx, ws, q_ws, k_ws, v_ws, d_out);
}

// Round 10
// 241.306 us; speedup vs baseline: 1.3073x; 1.3073x over previous
//
#include <hip/hip_runtime.h>

#define N_ 20480
#define EPS_ 1e-5f

typedef __bf16 bf16;
typedef __attribute__((ext_vector_type(8))) __bf16 bf16x8;
typedef __attribute__((ext_vector_type(4))) __bf16 bf16x4;
typedef __attribute__((ext_vector_type(4))) float f32x4;
typedef __attribute__((ext_vector_type(2))) float f32x2;

// ---- prep region byte offsets (total 45056 B, then q/k/v bf16 buffers) ----
#define WS_WG1   0        // bf16[4096]  Wg1 rows
#define WS_WG2   8192     // bf16[4096]  Wg2 rows
#define WS_PCST  16384    // f32x4[64]   {Wd2[c][0..2], bd2[c]}
#define WS_L1    17408    // f32x2[64]   {lng1_g, lng1_b}
#define WS_L2    17920    // f32x2[64]   {lng2_g, lng2_b}
#define WS_BG1   18432    // float[64]
#define WS_BG2   18688    // float[64]
#define WS_WQ    18944    // bf16[2048]  folded Wq' = Wq@W1
#define WS_WK    23040    // bf16[2048]
#define WS_WV    27136    // bf16[2048]
#define WS_WSC   31232    // bf16[2048]  BN-scale-folded Wsc'
#define WS_WMLP  35328    // bf16[4096]  BN-scale-folded Wmlp'
#define WS_BQ    43520    // float[64]   folded biases
#define WS_BK    43776
#define WS_BV    44032
#define WS_BSC   44288    // BN offset h for shortcut
#define WS_BMLP  44544    // BN offset h for mlp
#define WS_PD1   44800    // float[18]: Wd1[9], bd1[3], lnd1_g[3], lnd1_b[3]
#define WS_FLAG  44872    // int
#define WS_PREP  45056

template <typename T>
__device__ __forceinline__ float ldf(const T* p, size_t i) { return (float)p[i]; }

// dtype sniff: bf16 stream -> byte[15:8] of a u32 word is an exponent byte (~99% in [0x30,0x45));
// fp32 stream -> mid-mantissa byte (~8% hit). 4096 words of xyz decide it.
__device__ __forceinline__ int sniff_dtype(const unsigned int* xyz_raw) {
  const int t = threadIdx.x;
  __shared__ int cnt[256];
  int local = 0;
  for (int i = t; i < 4096; i += 256) {
    unsigned int wv = xyz_raw[i];
    unsigned int b1 = (wv >> 8) & 0xFFu;
    local += (b1 >= 0x30u && b1 < 0x45u) ? 1 : 0;
  }
  cnt[t] = local;
  __syncthreads();
  for (int s = 128; s > 0; s >>= 1) {
    if (t < s) cnt[t] += cnt[t + s];
    __syncthreads();
  }
  int r = (cnt[0] > 2048) ? 1 : 0;
  __syncthreads();
  return r;
}

// ---------------- K0: weight prep / folding (grid-stride, 64 blocks; computes flag itself) ----------------
template <typename T>
__device__ void prep_body(const T* W1, const T* b1, const T* Wq, const T* bq,
                          const T* Wk, const T* bk, const T* Wv, const T* bv,
                          const T* Wd1, const T* bd1, const T* lnd1_g, const T* lnd1_b,
                          const T* Wd2, const T* bd2,
                          const T* Wg1, const T* bg1, const T* lng1_g, const T* lng1_b,
                          const T* Wg2, const T* bg2, const T* lng2_g, const T* lng2_b,
                          const T* Wmlp, const T* bnm_g, const T* bnm_b, const T* bnm_m, const T* bnm_v,
                          const T* Wsc, const T* bns_g, const T* bns_b, const T* bns_m, const T* bns_v,
                          char* wsp) {
  const int tid = blockIdx.x * 256 + threadIdx.x;
  const int T_ = gridDim.x * 256;
  bf16* wg1bf = (bf16*)(wsp + WS_WG1);
  bf16* wg2bf = (bf16*)(wsp + WS_WG2);
  bf16* wmlpbf = (bf16*)(wsp + WS_WMLP);
  bf16* wscbf = (bf16*)(wsp + WS_WSC);
  bf16* wqbf = (bf16*)(wsp + WS_WQ);
  bf16* wkbf = (bf16*)(wsp + WS_WK);
  bf16* wvbf = (bf16*)(wsp + WS_WV);
  float* pcst = (float*)(wsp + WS_PCST);
  float* l1c = (float*)(wsp + WS_L1);
  float* l2c = (float*)(wsp + WS_L2);
  float* bg1f = (float*)(wsp + WS_BG1);
  float* bg2f = (float*)(wsp + WS_BG2);
  float* bqf = (float*)(wsp + WS_BQ);
  float* bkf = (float*)(wsp + WS_BK);
  float* bvf = (float*)(wsp + WS_BV);
  float* bscf = (float*)(wsp + WS_BSC);
  float* bmlpf = (float*)(wsp + WS_BMLP);
  float* pd1 = (float*)(wsp + WS_PD1);

  for (int i = tid; i < 4096; i += T_) {
    wg1bf[i] = (__bf16)ldf(Wg1, i);
    wg2bf[i] = (__bf16)ldf(Wg2, i);
    int c = i >> 6;
    float s = ldf(bnm_g, c) * rsqrtf(ldf(bnm_v, c) + EPS_);
    wmlpbf[i] = (__bf16)(s * ldf(Wmlp, i));
  }
  for (int i = tid; i < 2048; i += T_) {
    int c = i >> 5;
    float s = ldf(bns_g, c) * rsqrtf(ldf(bns_v, c) + EPS_);
    wscbf[i] = (__bf16)(s * ldf(Wsc, i));
  }
  // folded q/k/v weights: W' = W @ W1  (64x32)
  for (int o = tid; o < 2048; o += T_) {
    int c = o >> 5, d = o & 31;
    float aq = 0.f, ak = 0.f, av = 0.f;
    for (int cc = 0; cc < 64; ++cc) {
      float w1v = ldf(W1, cc * 32 + d);
      aq = fmaf(ldf(Wq, c * 64 + cc), w1v, aq);
      ak = fmaf(ldf(Wk, c * 64 + cc), w1v, ak);
      av = fmaf(ldf(Wv, c * 64 + cc), w1v, av);
    }
    wqbf[o] = (__bf16)aq; wkbf[o] = (__bf16)ak; wvbf[o] = (__bf16)av;
  }
  if (tid < 64) {
    int t = tid;
    pcst[t * 4 + 0] = ldf(Wd2, t * 3 + 0);
    pcst[t * 4 + 1] = ldf(Wd2, t * 3 + 1);
    pcst[t * 4 + 2] = ldf(Wd2, t * 3 + 2);
    pcst[t * 4 + 3] = ldf(bd2, t);
    l1c[t * 2 + 0] = ldf(lng1_g, t); l1c[t * 2 + 1] = ldf(lng1_b, t);
    l2c[t * 2 + 0] = ldf(lng2_g, t); l2c[t * 2 + 1] = ldf(lng2_b, t);
    bg1f[t] = ldf(bg1, t); bg2f[t] = ldf(bg2, t);
    float aq = ldf(bq, t), ak = ldf(bk, t), av = ldf(bv, t);
    for (int cc = 0; cc < 64; ++cc) {
      float b1v = ldf(b1, cc);
      aq = fmaf(ldf(Wq, t * 64 + cc), b1v, aq);
      ak = fmaf(ldf(Wk, t * 64 + cc), b1v, ak);
      av = fmaf(ldf(Wv, t * 64 + cc), b1v, av);
    }
    bqf[t] = aq; bkf[t] = ak; bvf[t] = av;
    float sm = ldf(bnm_g, t) * rsqrtf(ldf(bnm_v, t) + EPS_);
    bmlpf[t] = ldf(bnm_b, t) - ldf(bnm_m, t) * sm;
    float ss = ldf(bns_g, t) * rsqrtf(ldf(bns_v, t) + EPS_);
    bscf[t] = ldf(bns_b, t) - ldf(bns_m, t) * ss;
  }
  if (tid >= 64 && tid < 64 + 9) pd1[tid - 64] = ldf(Wd1, tid - 64);
  if (tid >= 80 && tid < 83) {
    int i = tid - 80;
    pd1[9 + i] = ldf(bd1, i);
    pd1[12 + i] = ldf(lnd1_g, i);
    pd1[15 + i] = ldf(lnd1_b, i);
  }
}

__launch_bounds__(256)
__global__ void prep_kernel(const void* xyz,
                            const void* W1, const void* b1, const void* Wq, const void* bq,
                            const void* Wk, const void* bk, const void* Wv, const void* bv,
                            const void* Wd1, const void* bd1, const void* lnd1_g, const void* lnd1_b,
                            const void* Wd2, const void* bd2,
                            const void* Wg1, const void* bg1, const void* lng1_g, const void* lng1_b,
                            const void* Wg2, const void* bg2, const void* lng2_g, const void* lng2_b,
                            const void* Wmlp, const void* bnm_g, const void* bnm_b, const void* bnm_m,
                            const void* bnm_v, const void* Wsc, const void* bns_g, const void* bns_b,
                            const void* bns_m, const void* bns_v, char* wsp) {
  int isbf = sniff_dtype((const unsigned int*)xyz);
  if (blockIdx.x == 0 && threadIdx.x == 0) *(int*)(wsp + WS_FLAG) = isbf;
  if (isbf)
    prep_body<bf16>((const bf16*)W1, (const bf16*)b1, (const bf16*)Wq, (const bf16*)bq,
                    (const bf16*)Wk, (const bf16*)bk, (const bf16*)Wv, (const bf16*)bv,
                    (const bf16*)Wd1, (const bf16*)bd1, (const bf16*)lnd1_g, (const bf16*)lnd1_b,
                    (const bf16*)Wd2, (const bf16*)bd2,
                    (const bf16*)Wg1, (const bf16*)bg1, (const bf16*)lng1_g, (const bf16*)lng1_b,
                    (const bf16*)Wg2, (const bf16*)bg2, (const bf16*)lng2_g, (const bf16*)lng2_b,
                    (const bf16*)Wmlp, (const bf16*)bnm_g, (const bf16*)bnm_b, (const bf16*)bnm_m,
                    (const bf16*)bnm_v, (const bf16*)Wsc, (const bf16*)bns_g, (const bf16*)bns_b,
                    (const bf16*)bns_m, (const bf16*)bns_v, wsp);
  else
    prep_body<float>((const float*)W1, (const float*)b1, (const float*)Wq, (const float*)bq,
                     (const float*)Wk, (const float*)bk, (const float*)Wv, (const float*)bv,
                     (const float*)Wd1, (const float*)bd1, (const float*)lnd1_g, (const float*)lnd1_b,
                     (const float*)Wd2, (const float*)bd2,
                     (const float*)Wg1, (const float*)bg1, (const float*)lng1_g, (const float*)lng1_b,
                     (const float*)Wg2, (const float*)bg2, (const float*)lng2_g, (const float*)lng2_b,
                     (const float*)Wmlp, (const float*)bnm_g, (const float*)bnm_b, (const float*)bnm_m,
                     (const float*)bnm_v, (const float*)Wsc, (const float*)bns_g, (const float*)bns_b,
                     (const float*)bns_m, (const float*)bns_v, wsp);
}

// ---------------- K1: MFMA q/k/v (folded weights), wave = 16 points ----------------
template <typename T>
__device__ void xqkv_body(const T* feat, const char* wsp,
                          bf16* q_ws, bf16* k_ws, bf16* v_ws, float (*tile)[68]) {
  const int t = threadIdx.x, w = t >> 6, lane = t & 63;
  const int m = lane & 15, g = lane >> 4;
  const int p0 = blockIdx.x * 64 + w * 16;
  const int b = p0 / N_, n0 = p0 % N_;
  const bf16* wqbf = (const bf16*)(wsp + WS_WQ);
  const bf16* wkbf = (const bf16*)(wsp + WS_WK);
  const bf16* wvbf = (const bf16*)(wsp + WS_WV);
  const float* bqf = (const float*)(wsp + WS_BQ);
  const float* bkf = (const float*)(wsp + WS_BK);
  const float* bvf = (const float*)(wsp + WS_BV);
  float (*tw)[68] = tile + w * 16;

  bf16x8 fa;
  #pragma unroll
  for (int j = 0; j < 8; ++j)
    fa[j] = (__bf16)ldf(feat, ((size_t)b * 32 + g * 8 + j) * N_ + n0 + m);

  auto matmul16 = [&](const bf16* wbf, const float* bias, float* ob) {
    #pragma unroll
    for (int tt = 0; tt < 4; ++tt) {
      bf16x8 wf = *(const bf16x8*)(wbf + (tt * 16 + m) * 32 + g * 8);
      float bb = bias[tt * 16 + m];
      f32x4 ci = {bb, bb, bb, bb};
      ci = __builtin_amdgcn_mfma_f32_16x16x32_bf16(fa, wf, ci, 0, 0, 0);
      #pragma unroll
      for (int r = 0; r < 4; ++r) tw[g * 4 + r][tt * 16 + m] = ci[r];
    }
    #pragma unroll
    for (int s = 0; s < 2; ++s) {
      f32x4 v0 = *(f32x4*)&tw[m][s * 32 + g * 8];
      f32x4 v1 = *(f32x4*)&tw[m][s * 32 + g * 8 + 4];
      #pragma unroll
      for (int r = 0; r < 4; ++r) { ob[s * 8 + r] = v0[r]; ob[s * 8 + 4 + r] = v1[r]; }
    }
  };
  float ob[16];
  bf16x8 o0, o1;
  matmul16(wqbf, bqf, ob);
  #pragma unroll
  for (int j = 0; j < 8; ++j) { o0[j] = (__bf16)ob[j]; o1[j] = (__bf16)ob[8 + j]; }
  *(bf16x8*)(q_ws + (size_t)(p0 + m) * 64 + g * 8) = o0;
  *(bf16x8*)(q_ws + (size_t)(p0 + m) * 64 + 32 + g * 8) = o1;
  matmul16(wkbf, bkf, ob);
  #pragma unroll
  for (int j = 0; j < 8; ++j) { o0[j] = (__bf16)ob[j]; o1[j] = (__bf16)ob[8 + j]; }
  *(bf16x8*)(k_ws + (size_t)(p0 + m) * 64 + g * 8) = o0;
  *(bf16x8*)(k_ws + (size_t)(p0 + m) * 64 + 32 + g * 8) = o1;
  matmul16(wvbf, bvf, ob);
  #pragma unroll
  for (int j = 0; j < 8; ++j) { o0[j] = (__bf16)ob[j]; o1[j] = (__bf16)ob[8 + j]; }
  *(bf16x8*)(v_ws + (size_t)(p0 + m) * 64 + g * 8) = o0;
  *(bf16x8*)(v_ws + (size_t)(p0 + m) * 64 + 32 + g * 8) = o1;
}

__launch_bounds__(256)
__global__ void xqkv_kernel(const void* feat, char* wsp,
                            bf16* q_ws, bf16* k_ws, bf16* v_ws) {
  __shared__ float tile[64][68];
  const int* flag = (const int*)(wsp + WS_FLAG);
  if (flag[0]) xqkv_body<bf16>((const bf16*)feat, wsp, q_ws, k_ws, v_ws, tile);
  else         xqkv_body<float>((const float*)feat, wsp, q_ws, k_ws, v_ws, tile);
}

// ---------------- K2: MFMA attention core, TWO independent points per wave (ILP) ----------------
// Round-8 body widened: every stage unrolled over P=0,1 so the two points' dependency
// chains interleave. VGPR target <=128 (4 waves/SIMD, same as round 8's 72-VGPR config);
// LDS 38.9 KB -> 4 blocks/CU matches the VGPR bound.
template <typename T>
__device__ void attn_body(const T* xyz, const int* nidx, const char* wsp,
                          bf16* qres, const bf16* k_ws, const bf16* v_ws,
                          f32x4* pcstL, f32x2* l1L, f32x2* l2L,
                          bf16 (*vpf)[72], bf16 (*scr)[72]) {
  const int t = threadIdx.x;
  ((float*)pcstL)[t] = ((const float*)(wsp + WS_PCST))[t];
  if (t < 128) ((float*)l1L)[t] = ((const float*)(wsp + WS_L1))[t];
  else if (t < 256) ((float*)l2L)[t - 128] = ((const float*)(wsp + WS_L2))[t - 128];
  __syncthreads();

  const int w = t >> 6, lane = t & 63, m = lane & 15, g = lane >> 4;
  const int pbase = blockIdx.x * 8 + w * 2;   // two consecutive points per wave

  const float* pd1 = (const float*)(wsp + WS_PD1);
  const float* bg1f = (const float*)(wsp + WS_BG1);
  const float* bg2f = (const float*)(wsp + WS_BG2);
  const bf16* wg1bf = (const bf16*)(wsp + WS_WG1);
  const bf16* wg2bf = (const bf16*)(wsp + WS_WG2);

  float bg1r[4], bg2r[4];
  #pragma unroll
  for (int tt = 0; tt < 4; ++tt) { bg1r[tt] = bg1f[tt * 16 + m]; bg2r[tt] = bg2f[tt * 16 + m]; }

  float a[2][16];

  // ---- phase 1: gather + pos + build a / vpf (per P; frags die inside) ----
  #pragma unroll
  for (int P = 0; P < 2; ++P) {
    const int p = pbase + P;
    const int b = p / N_;
    bf16 (*vw)[72] = vpf + (w * 2 + P) * 16;

    float xp = ldf(xyz, (size_t)p * 3 + 0);
    float yp = ldf(xyz, (size_t)p * 3 + 1);
    float zp = ldf(xyz, (size_t)p * 3 + 2);

    int idx = nidx[(size_t)p * 16 + m];
    size_t pg = (size_t)b * N_ + idx;
    bf16x8 kf0 = *(const bf16x8*)(k_ws + pg * 64 + g * 8);
    bf16x8 kf1 = *(const bf16x8*)(k_ws + pg * 64 + 32 + g * 8);
    bf16x8 vf0 = *(const bf16x8*)(v_ws + pg * 64 + g * 8);
    bf16x8 vf1 = *(const bf16x8*)(v_ws + pg * 64 + 32 + g * 8);
    bf16x8 qf0 = *(const bf16x8*)(qres + (size_t)p * 64 + g * 8);
    bf16x8 qf1 = *(const bf16x8*)(qres + (size_t)p * 64 + 32 + g * 8);
    float nx = ldf(xyz, pg * 3 + 0), ny = ldf(xyz, pg * 3 + 1), nz = ldf(xyz, pg * 3 + 2);

    float rx = xp - nx, ry = yp - ny, rz = zp - nz;
    float pp0 = pd1[0] * rx + pd1[1] * ry + pd1[2] * rz + pd1[9];
    float pp1 = pd1[3] * rx + pd1[4] * ry + pd1[5] * rz + pd1[10];
    float pp2 = pd1[6] * rx + pd1[7] * ry + pd1[8] * rz + pd1[11];
    float mu3 = (pp0 + pp1 + pp2) * (1.f / 3.f);
    float q0 = pp0 - mu3, q1 = pp1 - mu3, q2 = pp2 - mu3;
    float vr3 = (q0 * q0 + q1 * q1 + q2 * q2) * (1.f / 3.f);
    float rs3 = rsqrtf(vr3 + EPS_);
    float h0 = fmaxf(q0 * rs3 * pd1[12] + pd1[15], 0.f);
    float h1 = fmaxf(q1 * rs3 * pd1[13] + pd1[16], 0.f);
    float h2 = fmaxf(q2 * rs3 * pd1[14] + pd1[17], 0.f);

    #pragma unroll
    for (int s = 0; s < 2; ++s)
      #pragma unroll
      for (int half = 0; half < 2; ++half) {
        bf16x4 vb;
        #pragma unroll
        for (int q4 = 0; q4 < 4; ++q4) {
          int j = half * 4 + q4;
          int c = s * 32 + g * 8 + j;
          f32x4 pc = pcstL[c];
          float pos = fmaf(h0, pc[0], fmaf(h1, pc[1], fmaf(h2, pc[2], pc[3])));
          float kv = (float)((s == 0) ? kf0[j] : kf1[j]);
          float vv = (float)((s == 0) ? vf0[j] : vf1[j]);
          float qv = (float)((s == 0) ? qf0[j] : qf1[j]);
          vb[q4] = (__bf16)(vv + pos);
          a[P][s * 8 + j] = qv - kv + pos;
        }
        *(bf16x4*)&vw[m][s * 32 + g * 8 + half * 4] = vb;
      }
  }

  bf16x8 hf0[2], hf1[2];
  f32x4 acc[2][4];

  // ---- LN1 + relu -> A-frags (both P interleaved) ----
  #pragma unroll
  for (int P = 0; P < 2; ++P) {
    float s1 = 0.f, s2 = 0.f;
    #pragma unroll
    for (int i = 0; i < 16; ++i) { s1 += a[P][i]; s2 = fmaf(a[P][i], a[P][i], s2); }
    s1 += __shfl_xor(s1, 16); s2 += __shfl_xor(s2, 16);
    s1 += __shfl_xor(s1, 32); s2 += __shfl_xor(s2, 32);
    float mean = s1 * (1.f / 64.f);
    float var = s2 * (1.f / 64.f) - mean * mean;
    float rsv = rsqrtf(var + EPS_);
    #pragma unroll
    for (int s = 0; s < 2; ++s)
      #pragma unroll
      for (int j = 0; j < 8; ++j) {
        int c = s * 32 + g * 8 + j;
        f32x2 lc = l1L[c];
        float hh = fmaxf(fmaf((a[P][s * 8 + j] - mean) * rsv, lc[0], lc[1]), 0.f);
        if (s == 0) hf0[P][j] = (__bf16)hh; else hf1[P][j] = (__bf16)hh;
      }
  }
  // ---- GEMM1 (weight frags shared across both P) ----
  #pragma unroll
  for (int tt = 0; tt < 4; ++tt) {
    bf16x8 w0 = *(const bf16x8*)(wg1bf + (tt * 16 + m) * 64 + g * 8);
    bf16x8 w1 = *(const bf16x8*)(wg1bf + (tt * 16 + m) * 64 + 32 + g * 8);
    #pragma unroll
    for (int P = 0; P < 2; ++P) {
      f32x4 ci = {bg1r[tt], bg1r[tt], bg1r[tt], bg1r[tt]};
      ci = __builtin_amdgcn_mfma_f32_16x16x32_bf16(hf0[P], w0, ci, 0, 0, 0);
      ci = __builtin_amdgcn_mfma_f32_16x16x32_bf16(hf1[P], w1, ci, 0, 0, 0);
      acc[P][tt] = ci;
    }
  }
  // ---- D-layout -> A-layout roundtrip (bf16 LDS, same-wave in-order) ----
  #pragma unroll
  for (int P = 0; P < 2; ++P) {
    bf16 (*sw)[72] = scr + (w * 2 + P) * 16;
    #pragma unroll
    for (int tt = 0; tt < 4; ++tt)
      #pragma unroll
      for (int r = 0; r < 4; ++r)
        sw[g * 4 + r][tt * 16 + m] = (__bf16)acc[P][tt][r];
  }
  #pragma unroll
  for (int P = 0; P < 2; ++P) {
    bf16 (*sw)[72] = scr + (w * 2 + P) * 16;
    #pragma unroll
    for (int s = 0; s < 2; ++s) {
      bf16x8 av = *(bf16x8*)&sw[m][s * 32 + g * 8];
      #pragma unroll
      for (int j = 0; j < 8; ++j) a[P][s * 8 + j] = (float)av[j];
    }
  }
  // ---- LN2 + relu -> A-frags ----
  #pragma unroll
  for (int P = 0; P < 2; ++P) {
    float s1 = 0.f, s2 = 0.f;
    #pragma unroll
    for (int i = 0; i < 16; ++i) { s1 += a[P][i]; s2 = fmaf(a[P][i], a[P][i], s2); }
    s1 += __shfl_xor(s1, 16); s2 += __shfl_xor(s2, 16);
    s1 += __shfl_xor(s1, 32); s2 += __shfl_xor(s2, 32);
    float mean = s1 * (1.f / 64.f);
    float var = s2 * (1.f / 64.f) - mean * mean;
    float rsv = rsqrtf(var + EPS_);
    #pragma unroll
    for (int s = 0; s < 2; ++s)
      #pragma unroll
      for (int j = 0; j < 8; ++j) {
        int c = s * 32 + g * 8 + j;
        f32x2 lc = l2L[c];
        float hh = fmaxf(fmaf((a[P][s * 8 + j] - mean) * rsv, lc[0], lc[1]), 0.f);
        if (s == 0) hf0[P][j] = (__bf16)hh; else hf1[P][j] = (__bf16)hh;
      }
  }
  // ---- GEMM2 ----
  #pragma unroll
  for (int tt = 0; tt < 4; ++tt) {
    bf16x8 w0 = *(const bf16x8*)(wg2bf + (tt * 16 + m) * 64 + g * 8);
    bf16x8 w1 = *(const bf16x8*)(wg2bf + (tt * 16 + m) * 64 + 32 + g * 8);
    #pragma unroll
    for (int P = 0; P < 2; ++P) {
      f32x4 ci = {bg2r[tt], bg2r[tt], bg2r[tt], bg2r[tt]};
      ci = __builtin_amdgcn_mfma_f32_16x16x32_bf16(hf0[P], w0, ci, 0, 0, 0);
      ci = __builtin_amdgcn_mfma_f32_16x16x32_bf16(hf1[P], w1, ci, 0, 0, 0);
      acc[P][tt] = ci;
    }
  }
  // ---- softmax over 16 neighbors + weighted sum of (v+pos), store ----
  #pragma unroll
  for (int P = 0; P < 2; ++P) {
    const int p = pbase + P;
    bf16 (*vw)[72] = vpf + (w * 2 + P) * 16;
    float resv[4];
    #pragma unroll
    for (int tt = 0; tt < 4; ++tt) {
      f32x4 l = acc[P][tt];
      float mx = fmaxf(fmaxf(l[0], l[1]), fmaxf(l[2], l[3]));
      mx = fmaxf(mx, __shfl_xor(mx, 16));
      mx = fmaxf(mx, __shfl_xor(mx, 32));
      float x0 = __expf(l[0] - mx), x1 = __expf(l[1] - mx);
      float x2 = __expf(l[2] - mx), x3 = __expf(l[3] - mx);
      float ss = x0 + x1 + x2 + x3;
      ss += __shfl_xor(ss, 16); ss += __shfl_xor(ss, 32);
      int cc = tt * 16 + m;
      float part = x0 * (float)vw[g * 4 + 0][cc] + x1 * (float)vw[g * 4 + 1][cc]
                 + x2 * (float)vw[g * 4 + 2][cc] + x3 * (float)vw[g * 4 + 3][cc];
      part += __shfl_xor(part, 16); part += __shfl_xor(part, 32);
      resv[tt] = part / ss;
    }
    float outv = (g == 0) ? resv[0] : (g == 1) ? resv[1] : (g == 2) ? resv[2] : resv[3];
    qres[(size_t)p * 64 + lane] = (__bf16)outv;   // in-place over q (this wave read q above)
  }
}

__launch_bounds__(256)
__global__ void attn_kernel(const void* xyz, const int* __restrict__ nidx, char* wsp,
                            bf16* qres, const bf16* k_ws, const bf16* v_ws) {
  __shared__ f32x4 pcstL[64];      // 1024 B
  __shared__ f32x2 l1L[64];        // 512 B
  __shared__ f32x2 l2L[64];        // 512 B
  __shared__ bf16 vpf[128][72];    // 18432 B (8 points x 16 rows)
  __shared__ bf16 scr[128][72];    // 18432 B  -> total 38912 B -> 4 blocks/CU
  const int* flag = (const int*)(wsp + WS_FLAG);
  if (flag[0])
    attn_body<bf16>((const bf16*)xyz, nidx, wsp, qres, k_ws, v_ws, pcstL, l1L, l2L, vpf, scr);
  else
    attn_body<float>((const float*)xyz, nidx, wsp, qres, k_ws, v_ws, pcstL, l1L, l2L, vpf, scr);
}

// ---------------- K3: MFMA mlp + shortcut + leaky + transposed store ----------------
template <typename T>
__device__ void out_body(const T* feat, const bf16* res_ws, const char* wsp, T* out,
                         float (*tileT)[69]) {
  const int t = threadIdx.x, w = t >> 6, lane = t & 63;
  const int m = lane & 15, g = lane >> 4;
  const int p0blk = blockIdx.x * 64;
  const int b = p0blk / N_, n0 = p0blk % N_;
  const int p0w = p0blk + w * 16;
  const bf16* wmlpbf = (const bf16*)(wsp + WS_WMLP);
  const bf16* wscbf = (const bf16*)(wsp + WS_WSC);
  const float* bmlpf = (const float*)(wsp + WS_BMLP);
  const float* bscf = (const float*)(wsp + WS_BSC);

  bf16x8 ar0 = *(const bf16x8*)(res_ws + (size_t)(p0w + m) * 64 + g * 8);
  bf16x8 ar1 = *(const bf16x8*)(res_ws + (size_t)(p0w + m) * 64 + 32 + g * 8);
  bf16x8 af;
  #pragma unroll
  for (int j = 0; j < 8; ++j)
    af[j] = (__bf16)ldf(feat, ((size_t)b * 32 + g * 8 + j) * N_ + (n0 + w * 16) + m);

  #pragma unroll
  for (int tt = 0; tt < 4; ++tt) {
    bf16x8 wm0 = *(const bf16x8*)(wmlpbf + (tt * 16 + m) * 64 + g * 8);
    bf16x8 wm1 = *(const bf16x8*)(wmlpbf + (tt * 16 + m) * 64 + 32 + g * 8);
    bf16x8 wsf = *(const bf16x8*)(wscbf + (tt * 16 + m) * 32 + g * 8);
    float bm = bmlpf[tt * 16 + m], bs = bscf[tt * 16 + m];
    f32x4 cm = {bm, bm, bm, bm};
    cm = __builtin_amdgcn_mfma_f32_16x16x32_bf16(ar0, wm0, cm, 0, 0, 0);
    cm = __builtin_amdgcn_mfma_f32_16x16x32_bf16(ar1, wm1, cm, 0, 0, 0);
    f32x4 cs = {bs, bs, bs, bs};
    cs = __builtin_amdgcn_mfma_f32_16x16x32_bf16(af, wsf, cs, 0, 0, 0);
    #pragma unroll
    for (int r = 0; r < 4; ++r) {
      float o = fmaxf(cm[r], 0.f) + fmaxf(cs[r], 0.f);
      o = (o > 0.f) ? o : 0.2f * o;
      tileT[tt * 16 + m][w * 16 + g * 4 + r] = o;
    }
  }
  __syncthreads();
  const int ln = t & 63, grp = t >> 6;
  #pragma unroll
  for (int k = 0; k < 16; ++k) {
    int c2 = grp * 16 + k;
    out[((size_t)b * 64 + c2) * N_ + n0 + ln] = (T)tileT[c2][ln];
  }
}

__launch_bounds__(256)
__global__ void out_kernel(const void* feat, const bf16* res_ws, char* wsp, void* out) {
  __shared__ float tileT[64][69];
  const int* flag = (const int*)(wsp + WS_FLAG);
  if (flag[0]) out_body<bf16>((const bf16*)feat, res_ws, wsp, (bf16*)out, tileT);
  else         out_body<float>((const float*)feat, res_ws, wsp, (float*)out, tileT);
}

// ---------------- launcher ----------------
extern "C" void kernel_launch(void* const* d_in, const int* in_sizes, int n_in,
                              void* d_out, int out_size, void* d_ws, size_t ws_size,
                              hipStream_t stream) {
  const void* feature = d_in[0];
  const void* xyz     = d_in[1];
  const int*  nidx    = (const int*)d_in[34];

  char* ws = (char*)d_ws;
  bf16* q_ws = (bf16*)(ws + WS_PREP);                 // 5,242,880 B (q, then res in-place)
  bf16* k_ws = (bf16*)(ws + WS_PREP + 5242880);       // 5,242,880 B
  bf16* v_ws = (bf16*)(ws + WS_PREP + 10485760);      // 5,242,880 B  -> total 15.8 MB

  prep_kernel<<<64, 256, 0, stream>>>(xyz,
                                      d_in[2], d_in[3], d_in[4], d_in[5], d_in[6], d_in[7],
                                      d_in[8], d_in[9], d_in[10], d_in[11], d_in[12], d_in[13],
                                      d_in[14], d_in[15], d_in[16], d_in[17], d_in[18], d_in[19],
                                      d_in[20], d_in[21], d_in[22], d_in[23], d_in[24], d_in[25],
                                      d_in[26], d_in[27], d_in[28], d_in[29], d_in[30], d_in[31],
                                      d_in[32], d_in[33], ws);
  xqkv_kernel<<<640, 256, 0, stream>>>(feature, ws, q_ws, k_ws, v_ws);
  attn_kernel<<<5120, 256, 0, stream>>>(xyz, nidx, ws, q_ws, k_ws, v_ws);
  out_kernel<<<640, 256, 0, stream>>>(feature, q_ws, ws, d_out);
}

// Round 12
// 238.211 us; speedup vs baseline: 1.3243x; 1.0130x over previous
//
#include <hip/hip_runtime.h>

#define N_ 20480
#define EPS_ 1e-5f

typedef __bf16 bf16;
typedef __attribute__((ext_vector_type(8))) __bf16 bf16x8;
typedef __attribute__((ext_vector_type(4))) __bf16 bf16x4;
typedef __attribute__((ext_vector_type(4))) float f32x4;
typedef __attribute__((ext_vector_type(2))) float f32x2;

// ---- prep region byte offsets (total 45056 B, then q/k/v bf16 buffers) ----
#define WS_WG1   0        // bf16[4096]  Wg1 rows
#define WS_WG2   8192     // bf16[4096]  Wg2 rows
#define WS_PCST  16384    // f32x4[64]   {Wd2[c][0..2], bd2[c]}
#define WS_L1    17408    // f32x2[64]   {lng1_g, lng1_b}
#define WS_L2    17920    // f32x2[64]   {lng2_g, lng2_b}
#define WS_BG1   18432    // float[64]
#define WS_BG2   18688    // float[64]
#define WS_WQ    18944    // bf16[2048]  folded Wq' = Wq@W1
#define WS_WK    23040    // bf16[2048]
#define WS_WV    27136    // bf16[2048]
#define WS_WSC   31232    // bf16[2048]  BN-scale-folded Wsc'
#define WS_WMLP  35328    // bf16[4096]  BN-scale-folded Wmlp'
#define WS_BQ    43520    // float[64]   folded biases
#define WS_BK    43776
#define WS_BV    44032
#define WS_BSC   44288    // BN offset h for shortcut
#define WS_BMLP  44544    // BN offset h for mlp
#define WS_PD1   44800    // float[18]: Wd1[9], bd1[3], lnd1_g[3], lnd1_b[3]
#define WS_FLAG  44872    // int
#define WS_PREP  45056

template <typename T>
__device__ __forceinline__ float ldf(const T* p, size_t i) { return (float)p[i]; }

// dtype sniff: bf16 stream -> byte[15:8] of a u32 word is an exponent byte (~99% in [0x30,0x45));
// fp32 stream -> mid-mantissa byte (~8% hit). 4096 words of xyz decide it.
__device__ __forceinline__ int sniff_dtype(const unsigned int* xyz_raw) {
  const int t = threadIdx.x;
  __shared__ int cnt[256];
  int local = 0;
  for (int i = t; i < 4096; i += 256) {
    unsigned int wv = xyz_raw[i];
    unsigned int b1 = (wv >> 8) & 0xFFu;
    local += (b1 >= 0x30u && b1 < 0x45u) ? 1 : 0;
  }
  cnt[t] = local;
  __syncthreads();
  for (int s = 128; s > 0; s >>= 1) {
    if (t < s) cnt[t] += cnt[t + s];
    __syncthreads();
  }
  int r = (cnt[0] > 2048) ? 1 : 0;
  __syncthreads();
  return r;
}

// ---------------- K0: weight prep / folding (grid-stride, 64 blocks; computes flag itself) ----------------
template <typename T>
__device__ void prep_body(const T* W1, const T* b1, const T* Wq, const T* bq,
                          const T* Wk, const T* bk, const T* Wv, const T* bv,
                          const T* Wd1, const T* bd1, const T* lnd1_g, const T* lnd1_b,
                          const T* Wd2, const T* bd2,
                          const T* Wg1, const T* bg1, const T* lng1_g, const T* lng1_b,
                          const T* Wg2, const T* bg2, const T* lng2_g, const T* lng2_b,
                          const T* Wmlp, const T* bnm_g, const T* bnm_b, const T* bnm_m, const T* bnm_v,
                          const T* Wsc, const T* bns_g, const T* bns_b, const T* bns_m, const T* bns_v,
                          char* wsp) {
  const int tid = blockIdx.x * 256 + threadIdx.x;
  const int T_ = gridDim.x * 256;
  bf16* wg1bf = (bf16*)(wsp + WS_WG1);
  bf16* wg2bf = (bf16*)(wsp + WS_WG2);
  bf16* wmlpbf = (bf16*)(wsp + WS_WMLP);
  bf16* wscbf = (bf16*)(wsp + WS_WSC);
  bf16* wqbf = (bf16*)(wsp + WS_WQ);
  bf16* wkbf = (bf16*)(wsp + WS_WK);
  bf16* wvbf = (bf16*)(wsp + WS_WV);
  float* pcst = (float*)(wsp + WS_PCST);
  float* l1c = (float*)(wsp + WS_L1);
  float* l2c = (float*)(wsp + WS_L2);
  float* bg1f = (float*)(wsp + WS_BG1);
  float* bg2f = (float*)(wsp + WS_BG2);
  float* bqf = (float*)(wsp + WS_BQ);
  float* bkf = (float*)(wsp + WS_BK);
  float* bvf = (float*)(wsp + WS_BV);
  float* bscf = (float*)(wsp + WS_BSC);
  float* bmlpf = (float*)(wsp + WS_BMLP);
  float* pd1 = (float*)(wsp + WS_PD1);

  for (int i = tid; i < 4096; i += T_) {
    wg1bf[i] = (__bf16)ldf(Wg1, i);
    wg2bf[i] = (__bf16)ldf(Wg2, i);
    int c = i >> 6;
    float s = ldf(bnm_g, c) * rsqrtf(ldf(bnm_v, c) + EPS_);
    wmlpbf[i] = (__bf16)(s * ldf(Wmlp, i));
  }
  for (int i = tid; i < 2048; i += T_) {
    int c = i >> 5;
    float s = ldf(bns_g, c) * rsqrtf(ldf(bns_v, c) + EPS_);
    wscbf[i] = (__bf16)(s * ldf(Wsc, i));
  }
  // folded q/k/v weights: W' = W @ W1  (64x32)
  for (int o = tid; o < 2048; o += T_) {
    int c = o >> 5, d = o & 31;
    float aq = 0.f, ak = 0.f, av = 0.f;
    for (int cc = 0; cc < 64; ++cc) {
      float w1v = ldf(W1, cc * 32 + d);
      aq = fmaf(ldf(Wq, c * 64 + cc), w1v, aq);
      ak = fmaf(ldf(Wk, c * 64 + cc), w1v, ak);
      av = fmaf(ldf(Wv, c * 64 + cc), w1v, av);
    }
    wqbf[o] = (__bf16)aq; wkbf[o] = (__bf16)ak; wvbf[o] = (__bf16)av;
  }
  if (tid < 64) {
    int t = tid;
    pcst[t * 4 + 0] = ldf(Wd2, t * 3 + 0);
    pcst[t * 4 + 1] = ldf(Wd2, t * 3 + 1);
    pcst[t * 4 + 2] = ldf(Wd2, t * 3 + 2);
    pcst[t * 4 + 3] = ldf(bd2, t);
    l1c[t * 2 + 0] = ldf(lng1_g, t); l1c[t * 2 + 1] = ldf(lng1_b, t);
    l2c[t * 2 + 0] = ldf(lng2_g, t); l2c[t * 2 + 1] = ldf(lng2_b, t);
    bg1f[t] = ldf(bg1, t); bg2f[t] = ldf(bg2, t);
    float aq = ldf(bq, t), ak = ldf(bk, t), av = ldf(bv, t);
    for (int cc = 0; cc < 64; ++cc) {
      float b1v = ldf(b1, cc);
      aq = fmaf(ldf(Wq, t * 64 + cc), b1v, aq);
      ak = fmaf(ldf(Wk, t * 64 + cc), b1v, ak);
      av = fmaf(ldf(Wv, t * 64 + cc), b1v, av);
    }
    bqf[t] = aq; bkf[t] = ak; bvf[t] = av;
    float sm = ldf(bnm_g, t) * rsqrtf(ldf(bnm_v, t) + EPS_);
    bmlpf[t] = ldf(bnm_b, t) - ldf(bnm_m, t) * sm;
    float ss = ldf(bns_g, t) * rsqrtf(ldf(bns_v, t) + EPS_);
    bscf[t] = ldf(bns_b, t) - ldf(bns_m, t) * ss;
  }
  if (tid >= 64 && tid < 64 + 9) pd1[tid - 64] = ldf(Wd1, tid - 64);
  if (tid >= 80 && tid < 83) {
    int i = tid - 80;
    pd1[9 + i] = ldf(bd1, i);
    pd1[12 + i] = ldf(lnd1_g, i);
    pd1[15 + i] = ldf(lnd1_b, i);
  }
}

__launch_bounds__(256)
__global__ void prep_kernel(const void* xyz,
                            const void* W1, const void* b1, const void* Wq, const void* bq,
                            const void* Wk, const void* bk, const void* Wv, const void* bv,
                            const void* Wd1, const void* bd1, const void* lnd1_g, const void* lnd1_b,
                            const void* Wd2, const void* bd2,
                            const void* Wg1, const void* bg1, const void* lng1_g, const void* lng1_b,
                            const void* Wg2, const void* bg2, const void* lng2_g, const void* lng2_b,
                            const void* Wmlp, const void* bnm_g, const void* bnm_b, const void* bnm_m,
                            const void* bnm_v, const void* Wsc, const void* bns_g, const void* bns_b,
                            const void* bns_m, const void* bns_v, char* wsp) {
  int isbf = sniff_dtype((const unsigned int*)xyz);
  if (blockIdx.x == 0 && threadIdx.x == 0) *(int*)(wsp + WS_FLAG) = isbf;
  if (isbf)
    prep_body<bf16>((const bf16*)W1, (const bf16*)b1, (const bf16*)Wq, (const bf16*)bq,
                    (const bf16*)Wk, (const bf16*)bk, (const bf16*)Wv, (const bf16*)bv,
                    (const bf16*)Wd1, (const bf16*)bd1, (const bf16*)lnd1_g, (const bf16*)lnd1_b,
                    (const bf16*)Wd2, (const bf16*)bd2,
                    (const bf16*)Wg1, (const bf16*)bg1, (const bf16*)lng1_g, (const bf16*)lng1_b,
                    (const bf16*)Wg2, (const bf16*)bg2, (const bf16*)lng2_g, (const bf16*)lng2_b,
                    (const bf16*)Wmlp, (const bf16*)bnm_g, (const bf16*)bnm_b, (const bf16*)bnm_m,
                    (const bf16*)bnm_v, (const bf16*)Wsc, (const bf16*)bns_g, (const bf16*)bns_b,
                    (const bf16*)bns_m, (const bf16*)bns_v, wsp);
  else
    prep_body<float>((const float*)W1, (const float*)b1, (const float*)Wq, (const float*)bq,
                     (const float*)Wk, (const float*)bk, (const float*)Wv, (const float*)bv,
                     (const float*)Wd1, (const float*)bd1, (const float*)lnd1_g, (const float*)lnd1_b,
                     (const float*)Wd2, (const float*)bd2,
                     (const float*)Wg1, (const float*)bg1, (const float*)lng1_g, (const float*)lng1_b,
                     (const float*)Wg2, (const float*)bg2, (const float*)lng2_g, (const float*)lng2_b,
                     (const float*)Wmlp, (const float*)bnm_g, (const float*)bnm_b, (const float*)bnm_m,
                     (const float*)bnm_v, (const float*)Wsc, (const float*)bns_g, (const float*)bns_b,
                     (const float*)bns_m, (const float*)bns_v, wsp);
}

// ---------------- K1: MFMA q/k/v (folded weights), one wave per block = 16 points ----------------
// 2560 single-wave blocks (10/CU) instead of 640x4-wave (2.5/CU): better load balance/tail.
template <typename T>
__device__ void xqkv_body(const T* feat, const char* wsp,
                          bf16* q_ws, bf16* k_ws, bf16* v_ws, float (*tw)[68]) {
  const int lane = threadIdx.x & 63;
  const int m = lane & 15, g = lane >> 4;
  const int p0 = blockIdx.x * 16;
  const int b = p0 / N_, n0 = p0 % N_;
  const bf16* wqbf = (const bf16*)(wsp + WS_WQ);
  const bf16* wkbf = (const bf16*)(wsp + WS_WK);
  const bf16* wvbf = (const bf16*)(wsp + WS_WV);
  const float* bqf = (const float*)(wsp + WS_BQ);
  const float* bkf = (const float*)(wsp + WS_BK);
  const float* bvf = (const float*)(wsp + WS_BV);

  bf16x8 fa;
  #pragma unroll
  for (int j = 0; j < 8; ++j)
    fa[j] = (__bf16)ldf(feat, ((size_t)b * 32 + g * 8 + j) * N_ + n0 + m);

  auto matmul16 = [&](const bf16* wbf, const float* bias, float* ob) {
    #pragma unroll
    for (int tt = 0; tt < 4; ++tt) {
      bf16x8 wf = *(const bf16x8*)(wbf + (tt * 16 + m) * 32 + g * 8);
      float bb = bias[tt * 16 + m];
      f32x4 ci = {bb, bb, bb, bb};
      ci = __builtin_amdgcn_mfma_f32_16x16x32_bf16(fa, wf, ci, 0, 0, 0);
      #pragma unroll
      for (int r = 0; r < 4; ++r) tw[g * 4 + r][tt * 16 + m] = ci[r];
    }
    // same-wave LDS roundtrip (in-order)
    #pragma unroll
    for (int s = 0; s < 2; ++s) {
      f32x4 v0 = *(f32x4*)&tw[m][s * 32 + g * 8];
      f32x4 v1 = *(f32x4*)&tw[m][s * 32 + g * 8 + 4];
      #pragma unroll
      for (int r = 0; r < 4; ++r) { ob[s * 8 + r] = v0[r]; ob[s * 8 + 4 + r] = v1[r]; }
    }
  };
  float ob[16];
  bf16x8 o0, o1;
  matmul16(wqbf, bqf, ob);
  #pragma unroll
  for (int j = 0; j < 8; ++j) { o0[j] = (__bf16)ob[j]; o1[j] = (__bf16)ob[8 + j]; }
  *(bf16x8*)(q_ws + (size_t)(p0 + m) * 64 + g * 8) = o0;
  *(bf16x8*)(q_ws + (size_t)(p0 + m) * 64 + 32 + g * 8) = o1;
  matmul16(wkbf, bkf, ob);
  #pragma unroll
  for (int j = 0; j < 8; ++j) { o0[j] = (__bf16)ob[j]; o1[j] = (__bf16)ob[8 + j]; }
  *(bf16x8*)(k_ws + (size_t)(p0 + m) * 64 + g * 8) = o0;
  *(bf16x8*)(k_ws + (size_t)(p0 + m) * 64 + 32 + g * 8) = o1;
  matmul16(wvbf, bvf, ob);
  #pragma unroll
  for (int j = 0; j < 8; ++j) { o0[j] = (__bf16)ob[j]; o1[j] = (__bf16)ob[8 + j]; }
  *(bf16x8*)(v_ws + (size_t)(p0 + m) * 64 + g * 8) = o0;
  *(bf16x8*)(v_ws + (size_t)(p0 + m) * 64 + 32 + g * 8) = o1;
}

__launch_bounds__(64)
__global__ void xqkv_kernel(const void* feat, char* wsp,
                            bf16* q_ws, bf16* k_ws, bf16* v_ws) {
  __shared__ float tile[16][68];
  const int* flag = (const int*)(wsp + WS_FLAG);
  if (flag[0]) xqkv_body<bf16>((const bf16*)feat, wsp, q_ws, k_ws, v_ws, tile);
  else         xqkv_body<float>((const float*)feat, wsp, q_ws, k_ws, v_ws, tile);
}

// ---------------- K2: MFMA attention core, TWO independent points per wave (r10-proven) ----------------
template <typename T>
__device__ void attn_body(const T* xyz, const int* nidx, const char* wsp,
                          bf16* qres, const bf16* k_ws, const bf16* v_ws,
                          f32x4* pcstL, f32x2* l1L, f32x2* l2L,
                          bf16 (*vpf)[72], bf16 (*scr)[72]) {
  const int t = threadIdx.x;
  ((float*)pcstL)[t] = ((const float*)(wsp + WS_PCST))[t];
  if (t < 128) ((float*)l1L)[t] = ((const float*)(wsp + WS_L1))[t];
  else if (t < 256) ((float*)l2L)[t - 128] = ((const float*)(wsp + WS_L2))[t - 128];
  __syncthreads();

  const int w = t >> 6, lane = t & 63, m = lane & 15, g = lane >> 4;
  const int pbase = blockIdx.x * 8 + w * 2;   // two consecutive points per wave

  const float* pd1 = (const float*)(wsp + WS_PD1);
  const float* bg1f = (const float*)(wsp + WS_BG1);
  const float* bg2f = (const float*)(wsp + WS_BG2);
  const bf16* wg1bf = (const bf16*)(wsp + WS_WG1);
  const bf16* wg2bf = (const bf16*)(wsp + WS_WG2);

  float bg1r[4], bg2r[4];
  #pragma unroll
  for (int tt = 0; tt < 4; ++tt) { bg1r[tt] = bg1f[tt * 16 + m]; bg2r[tt] = bg2f[tt * 16 + m]; }

  float a[2][16];

  // ---- phase 1: gather + pos + build a / vpf (per P; frags die inside) ----
  #pragma unroll
  for (int P = 0; P < 2; ++P) {
    const int p = pbase + P;
    const int b = p / N_;
    bf16 (*vw)[72] = vpf + (w * 2 + P) * 16;

    float xp = ldf(xyz, (size_t)p * 3 + 0);
    float yp = ldf(xyz, (size_t)p * 3 + 1);
    float zp = ldf(xyz, (size_t)p * 3 + 2);

    int idx = nidx[(size_t)p * 16 + m];
    size_t pg = (size_t)b * N_ + idx;
    bf16x8 kf0 = *(const bf16x8*)(k_ws + pg * 64 + g * 8);
    bf16x8 kf1 = *(const bf16x8*)(k_ws + pg * 64 + 32 + g * 8);
    bf16x8 vf0 = *(const bf16x8*)(v_ws + pg * 64 + g * 8);
    bf16x8 vf1 = *(const bf16x8*)(v_ws + pg * 64 + 32 + g * 8);
    bf16x8 qf0 = *(const bf16x8*)(qres + (size_t)p * 64 + g * 8);
    bf16x8 qf1 = *(const bf16x8*)(qres + (size_t)p * 64 + 32 + g * 8);
    float nx = ldf(xyz, pg * 3 + 0), ny = ldf(xyz, pg * 3 + 1), nz = ldf(xyz, pg * 3 + 2);

    float rx = xp - nx, ry = yp - ny, rz = zp - nz;
    float pp0 = pd1[0] * rx + pd1[1] * ry + pd1[2] * rz + pd1[9];
    float pp1 = pd1[3] * rx + pd1[4] * ry + pd1[5] * rz + pd1[10];
    float pp2 = pd1[6] * rx + pd1[7] * ry + pd1[8] * rz + pd1[11];
    float mu3 = (pp0 + pp1 + pp2) * (1.f / 3.f);
    float q0 = pp0 - mu3, q1 = pp1 - mu3, q2 = pp2 - mu3;
    float vr3 = (q0 * q0 + q1 * q1 + q2 * q2) * (1.f / 3.f);
    float rs3 = rsqrtf(vr3 + EPS_);
    float h0 = fmaxf(q0 * rs3 * pd1[12] + pd1[15], 0.f);
    float h1 = fmaxf(q1 * rs3 * pd1[13] + pd1[16], 0.f);
    float h2 = fmaxf(q2 * rs3 * pd1[14] + pd1[17], 0.f);

    #pragma unroll
    for (int s = 0; s < 2; ++s)
      #pragma unroll
      for (int half = 0; half < 2; ++half) {
        bf16x4 vb;
        #pragma unroll
        for (int q4 = 0; q4 < 4; ++q4) {
          int j = half * 4 + q4;
          int c = s * 32 + g * 8 + j;
          f32x4 pc = pcstL[c];
          float pos = fmaf(h0, pc[0], fmaf(h1, pc[1], fmaf(h2, pc[2], pc[3])));
          float kv = (float)((s == 0) ? kf0[j] : kf1[j]);
          float vv = (float)((s == 0) ? vf0[j] : vf1[j]);
          float qv = (float)((s == 0) ? qf0[j] : qf1[j]);
          vb[q4] = (__bf16)(vv + pos);
          a[P][s * 8 + j] = qv - kv + pos;
        }
        *(bf16x4*)&vw[m][s * 32 + g * 8 + half * 4] = vb;
      }
  }

  bf16x8 hf0[2], hf1[2];
  f32x4 acc[2][4];

  // ---- LN1 + relu -> A-frags (both P interleaved) ----
  #pragma unroll
  for (int P = 0; P < 2; ++P) {
    float s1 = 0.f, s2 = 0.f;
    #pragma unroll
    for (int i = 0; i < 16; ++i) { s1 += a[P][i]; s2 = fmaf(a[P][i], a[P][i], s2); }
    s1 += __shfl_xor(s1, 16); s2 += __shfl_xor(s2, 16);
    s1 += __shfl_xor(s1, 32); s2 += __shfl_xor(s2, 32);
    float mean = s1 * (1.f / 64.f);
    float var = s2 * (1.f / 64.f) - mean * mean;
    float rsv = rsqrtf(var + EPS_);
    #pragma unroll
    for (int s = 0; s < 2; ++s)
      #pragma unroll
      for (int j = 0; j < 8; ++j) {
        int c = s * 32 + g * 8 + j;
        f32x2 lc = l1L[c];
        float hh = fmaxf(fmaf((a[P][s * 8 + j] - mean) * rsv, lc[0], lc[1]), 0.f);
        if (s == 0) hf0[P][j] = (__bf16)hh; else hf1[P][j] = (__bf16)hh;
      }
  }
  // ---- GEMM1 (weight frags shared across both P) ----
  #pragma unroll
  for (int tt = 0; tt < 4; ++tt) {
    bf16x8 w0 = *(const bf16x8*)(wg1bf + (tt * 16 + m) * 64 + g * 8);
    bf16x8 w1 = *(const bf16x8*)(wg1bf + (tt * 16 + m) * 64 + 32 + g * 8);
    #pragma unroll
    for (int P = 0; P < 2; ++P) {
      f32x4 ci = {bg1r[tt], bg1r[tt], bg1r[tt], bg1r[tt]};
      ci = __builtin_amdgcn_mfma_f32_16x16x32_bf16(hf0[P], w0, ci, 0, 0, 0);
      ci = __builtin_amdgcn_mfma_f32_16x16x32_bf16(hf1[P], w1, ci, 0, 0, 0);
      acc[P][tt] = ci;
    }
  }
  // ---- D-layout -> A-layout roundtrip (bf16 LDS, same-wave in-order) ----
  #pragma unroll
  for (int P = 0; P < 2; ++P) {
    bf16 (*sw)[72] = scr + (w * 2 + P) * 16;
    #pragma unroll
    for (int tt = 0; tt < 4; ++tt)
      #pragma unroll
      for (int r = 0; r < 4; ++r)
        sw[g * 4 + r][tt * 16 + m] = (__bf16)acc[P][tt][r];
  }
  #pragma unroll
  for (int P = 0; P < 2; ++P) {
    bf16 (*sw)[72] = scr + (w * 2 + P) * 16;
    #pragma unroll
    for (int s = 0; s < 2; ++s) {
      bf16x8 av = *(bf16x8*)&sw[m][s * 32 + g * 8];
      #pragma unroll
      for (int j = 0; j < 8; ++j) a[P][s * 8 + j] = (float)av[j];
    }
  }
  // ---- LN2 + relu -> A-frags ----
  #pragma unroll
  for (int P = 0; P < 2; ++P) {
    float s1 = 0.f, s2 = 0.f;
    #pragma unroll
    for (int i = 0; i < 16; ++i) { s1 += a[P][i]; s2 = fmaf(a[P][i], a[P][i], s2); }
    s1 += __shfl_xor(s1, 16); s2 += __shfl_xor(s2, 16);
    s1 += __shfl_xor(s1, 32); s2 += __shfl_xor(s2, 32);
    float mean = s1 * (1.f / 64.f);
    float var = s2 * (1.f / 64.f) - mean * mean;
    float rsv = rsqrtf(var + EPS_);
    #pragma unroll
    for (int s = 0; s < 2; ++s)
      #pragma unroll
      for (int j = 0; j < 8; ++j) {
        int c = s * 32 + g * 8 + j;
        f32x2 lc = l2L[c];
        float hh = fmaxf(fmaf((a[P][s * 8 + j] - mean) * rsv, lc[0], lc[1]), 0.f);
        if (s == 0) hf0[P][j] = (__bf16)hh; else hf1[P][j] = (__bf16)hh;
      }
  }
  // ---- GEMM2 ----
  #pragma unroll
  for (int tt = 0; tt < 4; ++tt) {
    bf16x8 w0 = *(const bf16x8*)(wg2bf + (tt * 16 + m) * 64 + g * 8);
    bf16x8 w1 = *(const bf16x8*)(wg2bf + (tt * 16 + m) * 64 + 32 + g * 8);
    #pragma unroll
    for (int P = 0; P < 2; ++P) {
      f32x4 ci = {bg2r[tt], bg2r[tt], bg2r[tt], bg2r[tt]};
      ci = __builtin_amdgcn_mfma_f32_16x16x32_bf16(hf0[P], w0, ci, 0, 0, 0);
      ci = __builtin_amdgcn_mfma_f32_16x16x32_bf16(hf1[P], w1, ci, 0, 0, 0);
      acc[P][tt] = ci;
    }
  }
  // ---- softmax over 16 neighbors + weighted sum of (v+pos), store ----
  #pragma unroll
  for (int P = 0; P < 2; ++P) {
    const int p = pbase + P;
    bf16 (*vw)[72] = vpf + (w * 2 + P) * 16;
    float resv[4];
    #pragma unroll
    for (int tt = 0; tt < 4; ++tt) {
      f32x4 l = acc[P][tt];
      float mx = fmaxf(fmaxf(l[0], l[1]), fmaxf(l[2], l[3]));
      mx = fmaxf(mx, __shfl_xor(mx, 16));
      mx = fmaxf(mx, __shfl_xor(mx, 32));
      float x0 = __expf(l[0] - mx), x1 = __expf(l[1] - mx);
      float x2 = __expf(l[2] - mx), x3 = __expf(l[3] - mx);
      float ss = x0 + x1 + x2 + x3;
      ss += __shfl_xor(ss, 16); ss += __shfl_xor(ss, 32);
      int cc = tt * 16 + m;
      float part = x0 * (float)vw[g * 4 + 0][cc] + x1 * (float)vw[g * 4 + 1][cc]
                 + x2 * (float)vw[g * 4 + 2][cc] + x3 * (float)vw[g * 4 + 3][cc];
      part += __shfl_xor(part, 16); part += __shfl_xor(part, 32);
      resv[tt] = part / ss;
    }
    float outv = (g == 0) ? resv[0] : (g == 1) ? resv[1] : (g == 2) ? resv[2] : resv[3];
    qres[(size_t)p * 64 + lane] = (__bf16)outv;   // in-place over q (this wave read q above)
  }
}

__launch_bounds__(256)
__global__ void attn_kernel(const void* xyz, const int* __restrict__ nidx, char* wsp,
                            bf16* qres, const bf16* k_ws, const bf16* v_ws) {
  __shared__ f32x4 pcstL[64];      // 1024 B
  __shared__ f32x2 l1L[64];        // 512 B
  __shared__ f32x2 l2L[64];        // 512 B
  __shared__ bf16 vpf[128][72];    // 18432 B (8 points x 16 rows)
  __shared__ bf16 scr[128][72];    // 18432 B  -> total 38912 B -> 4 blocks/CU
  const int* flag = (const int*)(wsp + WS_FLAG);
  if (flag[0])
    attn_body<bf16>((const bf16*)xyz, nidx, wsp, qres, k_ws, v_ws, pcstL, l1L, l2L, vpf, scr);
  else
    attn_body<float>((const float*)xyz, nidx, wsp, qres, k_ws, v_ws, pcstL, l1L, l2L, vpf, scr);
}

// ---------------- K3: MFMA mlp + shortcut + leaky + transposed store (r10-proven) ----------------
template <typename T>
__device__ void out_body(const T* feat, const bf16* res_ws, const char* wsp, T* out,
                         float (*tileT)[69]) {
  const int t = threadIdx.x, w = t >> 6, lane = t & 63;
  const int m = lane & 15, g = lane >> 4;
  const int p0blk = blockIdx.x * 64;
  const int b = p0blk / N_, n0 = p0blk % N_;
  const int p0w = p0blk + w * 16;
  const bf16* wmlpbf = (const bf16*)(wsp + WS_WMLP);
  const bf16* wscbf = (const bf16*)(wsp + WS_WSC);
  const float* bmlpf = (const float*)(wsp + WS_BMLP);
  const float* bscf = (const float*)(wsp + WS_BSC);

  bf16x8 ar0 = *(const bf16x8*)(res_ws + (size_t)(p0w + m) * 64 + g * 8);
  bf16x8 ar1 = *(const bf16x8*)(res_ws + (size_t)(p0w + m) * 64 + 32 + g * 8);
  bf16x8 af;
  #pragma unroll
  for (int j = 0; j < 8; ++j)
    af[j] = (__bf16)ldf(feat, ((size_t)b * 32 + g * 8 + j) * N_ + (n0 + w * 16) + m);

  #pragma unroll
  for (int tt = 0; tt < 4; ++tt) {
    bf16x8 wm0 = *(const bf16x8*)(wmlpbf + (tt * 16 + m) * 64 + g * 8);
    bf16x8 wm1 = *(const bf16x8*)(wmlpbf + (tt * 16 + m) * 64 + 32 + g * 8);
    bf16x8 wsf = *(const bf16x8*)(wscbf + (tt * 16 + m) * 32 + g * 8);
    float bm = bmlpf[tt * 16 + m], bs = bscf[tt * 16 + m];
    f32x4 cm = {bm, bm, bm, bm};
    cm = __builtin_amdgcn_mfma_f32_16x16x32_bf16(ar0, wm0, cm, 0, 0, 0);
    cm = __builtin_amdgcn_mfma_f32_16x16x32_bf16(ar1, wm1, cm, 0, 0, 0);
    f32x4 cs = {bs, bs, bs, bs};
    cs = __builtin_amdgcn_mfma_f32_16x16x32_bf16(af, wsf, cs, 0, 0, 0);
    #pragma unroll
    for (int r = 0; r < 4; ++r) {
      float o = fmaxf(cm[r], 0.f) + fmaxf(cs[r], 0.f);
      o = (o > 0.f) ? o : 0.2f * o;
      tileT[tt * 16 + m][w * 16 + g * 4 + r] = o;
    }
  }
  __syncthreads();
  const int ln = t & 63, grp = t >> 6;
  #pragma unroll
  for (int k = 0; k < 16; ++k) {
    int c2 = grp * 16 + k;
    out[((size_t)b * 64 + c2) * N_ + n0 + ln] = (T)tileT[c2][ln];
  }
}

__launch_bounds__(256)
__global__ void out_kernel(const void* feat, const bf16* res_ws, char* wsp, void* out) {
  __shared__ float tileT[64][69];
  const int* flag = (const int*)(wsp + WS_FLAG);
  if (flag[0]) out_body<bf16>((const bf16*)feat, res_ws, wsp, (bf16*)out, tileT);
  else         out_body<float>((const float*)feat, res_ws, wsp, (float*)out, tileT);
}

// ---------------- launcher ----------------
extern "C" void kernel_launch(void* const* d_in, const int* in_sizes, int n_in,
                              void* d_out, int out_size, void* d_ws, size_t ws_size,
                              hipStream_t stream) {
  const void* feature = d_in[0];
  const void* xyz     = d_in[1];
  const int*  nidx    = (const int*)d_in[34];

  char* ws = (char*)d_ws;
  bf16* q_ws = (bf16*)(ws + WS_PREP);                 // 5,242,880 B (q, then res in-place)
  bf16* k_ws = (bf16*)(ws + WS_PREP + 5242880);       // 5,242,880 B
  bf16* v_ws = (bf16*)(ws + WS_PREP + 10485760);      // 5,242,880 B  -> total 15.8 MB

  prep_kernel<<<64, 256, 0, stream>>>(xyz,
                                      d_in[2], d_in[3], d_in[4], d_in[5], d_in[6], d_in[7],
                                      d_in[8], d_in[9], d_in[10], d_in[11], d_in[12], d_in[13],
                                      d_in[14], d_in[15], d_in[16], d_in[17], d_in[18], d_in[19],
                                      d_in[20], d_in[21], d_in[22], d_in[23], d_in[24], d_in[25],
                                      d_in[26], d_in[27], d_in[28], d_in[29], d_in[30], d_in[31],
                                      d_in[32], d_in[33], ws);
  xqkv_kernel<<<2560, 64, 0, stream>>>(feature, ws, q_ws, k_ws, v_ws);
  attn_kernel<<<5120, 256, 0, stream>>>(xyz, nidx, ws, q_ws, k_ws, v_ws);
  out_kernel<<<640, 256, 0, stream>>>(feature, q_ws, ws, d_out);
}